// Round 3
// baseline (37.781 us; speedup 1.0000x reference)
//
#include <hip/hip_runtime.h>
#include <hip/hip_bf16.h>

// DynaConv as 2 kernels:
//  UP: W2b reshape->bf16 [1024][288]; fused unfold -> u_lds; u stored to ws in
//      MFMA-frag order [kb][mtile][rf][lane][8]; hh=tanh(W1 u+b1), t=b2 u+bias
//      via 16x16x32 MFMA (W1/b2 staged to padded LDS as bf16).
//  G : tiled GEMM S[p, o*32+h] = sum_j u[p,j] W2b[o*32+h, j], M-tile 256 x
//      N-tile 128, K=288. B in registers (loaded once), A double-buffered via
//      global_load_lds. Epilogue: out[p,o] = sum_h hh[p,h]*S + t[p,o].

#define CKK 288
#define SJ  296   // padded row stride (bf16) for LDS tiles

typedef __attribute__((ext_vector_type(8))) short short8;
typedef __attribute__((ext_vector_type(4))) float f32x4;

// ws layout
#define W2B_OFF 0                          // bf16 [1024][288]
#define U_OFF   294912                     // bf16 [9][32][16][64][8]
#define U_ELEMS (9 * 8192 * 32)
#define HH_BYTE ((U_OFF + U_ELEMS) * 2)    // f32 [8192][32]
#define T_BYTE  (HH_BYTE + 8192 * 32 * 4)  // f32 [32][8192] (bias folded in)

__global__ __launch_bounds__(512) void dynaconv_up(
    const float* __restrict__ x, const float* __restrict__ W1,
    const float* __restrict__ b1, const float* __restrict__ W2,
    const float* __restrict__ b2, const float* __restrict__ bias,
    char* __restrict__ wsraw)
{
    __hip_bfloat16* wsb = (__hip_bfloat16*)wsraw;
    float* hh_ws = (float*)(wsraw + HH_BYTE);
    float* t_ws  = (float*)(wsraw + T_BYTE);

    __shared__ __align__(16) __hip_bfloat16 u_lds[32 * SJ];
    __shared__ __align__(16) __hip_bfloat16 w1_lds[32 * SJ];
    __shared__ __align__(16) __hip_bfloat16 b2_lds[32 * SJ];

    const int t  = threadIdx.x;
    const int w  = t >> 6, l = t & 63, lg = l >> 4, lr = l & 15;
    const int g0 = blockIdx.x * 32;
    const int b  = g0 >> 12, l0 = g0 & 4095, y = l0 >> 6, wx0 = l0 & 63;

    // ---- W2b reshape/convert (grid-strided across all 131072 threads) ----
    {
        int gid = blockIdx.x * 512 + t;
        #pragma unroll
        for (int k = 0; k < 3; ++k) {
            int idx = k * 131072 + gid;
            if (idx < 294912) {
                int n = idx / CKK, j = idx - n * CKK;
                int o = n >> 5, h = n & 31;
                wsb[W2B_OFF + idx] = __float2bfloat16(W2[(o * CKK + j) * 32 + h]);
            }
        }
    }

    // ---- W1, b2 -> padded LDS bf16 ----
    #pragma unroll
    for (int k = 0; k < 18; ++k) {
        int idx = k * 512 + t;               // 9216 elems each
        int row = idx / CKK, jj = idx - row * CKK;
        w1_lds[row * SJ + jj] = __float2bfloat16(W1[idx]);
        b2_lds[row * SJ + jj] = __float2bfloat16(b2[idx]);
    }

    // ---- fused unfold -> u_lds[p][j] ----
    #pragma unroll
    for (int k = 0; k < 18; ++k) {
        int idx = k * 512 + t;               // 32p * 288j
        int j = idx >> 5, p = idx & 31;
        int c = j / 9, r = j - c * 9;
        int ki = r / 3, kj = r - ki * 3;
        int y2 = y + ki - 1, x2 = wx0 + p + kj - 1;
        float v = 0.f;
        if ((unsigned)y2 < 64u && (unsigned)x2 < 64u)
            v = x[((b * 32 + c) * 64 + y2) * 64 + x2];
        u_lds[p * SJ + j] = __float2bfloat16(v);
    }
    __syncthreads();

    // ---- store u in G's fragment order: [kb][mt][rf][l][8] ----
    {
        const int mt  = blockIdx.x >> 3;          // m-tile (256 pixels)
        const int rf0 = (blockIdx.x * 2) & 15;    // first 16-row frag in tile
        #pragma unroll
        for (int k = 0; k < 3; ++k) {
            int idx = k * 512 + t;                // 1152 16B-chunks per block
            if (idx < 1152) {
                int kb = idx >> 7, rem = idx & 127;
                int rfl = rem >> 6, ll = rem & 63;
                int p = rfl * 16 + (ll & 15);
                int j = kb * 32 + ((ll >> 4) << 3);
                short8 v = *(const short8*)(u_lds + p * SJ + j);
                int dst16 = ((kb * 32 + mt) * 16 + rf0 + rfl) * 64 + ll;
                *(short8*)(wsb + U_OFF + dst16 * 8) = v;
            }
        }
    }

    // ---- hh & t via MFMA (waves 0-3) ----
    if (w < 4) {
        const __hip_bfloat16* Bl = (w < 2) ? b2_lds : w1_lds;
        const int col = (w & 1) * 16 + lr;
        f32x4 acc0 = {0.f,0.f,0.f,0.f}, acc1 = {0.f,0.f,0.f,0.f};
        #pragma unroll
        for (int kb = 0; kb < 9; ++kb) {
            short8 bf = *(const short8*)(Bl + col * SJ + kb * 32 + lg * 8);
            short8 a0 = *(const short8*)(u_lds + lr * SJ + kb * 32 + lg * 8);
            short8 a1 = *(const short8*)(u_lds + (16 + lr) * SJ + kb * 32 + lg * 8);
            acc0 = __builtin_amdgcn_mfma_f32_16x16x32_bf16(a0, bf, acc0, 0, 0, 0);
            acc1 = __builtin_amdgcn_mfma_f32_16x16x32_bf16(a1, bf, acc1, 0, 0, 0);
        }
        if (w < 2) {  // t + bias, transposed layout [o][pixel]
            float bv = bias[col];
            #pragma unroll
            for (int r = 0; r < 4; ++r) {
                t_ws[col * 8192 + g0 + lg * 4 + r]      = acc0[r] + bv;
                t_ws[col * 8192 + g0 + 16 + lg * 4 + r] = acc1[r] + bv;
            }
        } else {      // hh, layout [pixel][h]
            float b1v = b1[col];
            #pragma unroll
            for (int r = 0; r < 4; ++r) {
                hh_ws[(g0 + lg * 4 + r) * 32 + col]      = tanhf(acc0[r] + b1v);
                hh_ws[(g0 + 16 + lg * 4 + r) * 32 + col] = tanhf(acc1[r] + b1v);
            }
        }
    }
}

__device__ __forceinline__ void stage_a(const __hip_bfloat16* __restrict__ src,
                                        __hip_bfloat16* dst, int w, int l)
{
    // 16KB chunk: 8 waves x 2 calls x (64 lanes x 16B)
    #pragma unroll
    for (int c = 0; c < 2; ++c) {
        const __hip_bfloat16* g = src + (w * 128 + c * 64 + l) * 8;
        __hip_bfloat16* s = dst + (w * 128 + c * 64) * 8;  // wave-uniform base
        __builtin_amdgcn_global_load_lds(
            (const __attribute__((address_space(1))) void*)g,
            (__attribute__((address_space(3))) void*)s, 16, 0, 0);
    }
}

__global__ __launch_bounds__(512) void dynaconv_g(
    const char* __restrict__ wsraw, float* __restrict__ out)
{
    const __hip_bfloat16* W2b  = (const __hip_bfloat16*)wsraw;
    const __hip_bfloat16* u_ws = (const __hip_bfloat16*)wsraw + U_OFF;
    const float* hh_ws = (const float*)(wsraw + HH_BYTE);
    const float* t_ws  = (const float*)(wsraw + T_BYTE);

    __shared__ __align__(16) __hip_bfloat16 abuf[2][8192]; // 2 x 16KB
    __shared__ float hh_lds[256 * 34];
    __shared__ float o_lds[256 * 5];

    const int t = threadIdx.x;
    const int w = t >> 6, l = t & 63, lg = l >> 4, lr = l & 15;
    const int mw = w >> 2, nw = w & 3;           // 2 M-waves x 4 N-waves
    const int mtile = blockIdx.x >> 3, ntile = blockIdx.x & 7;
    const int m0 = mtile * 256, o0 = ntile * 4;
    const int o = o0 + nw;                       // this wave's output channel

    // ---- B into registers, once: breg[kb][nf] ----
    short8 breg[9][2];
    #pragma unroll
    for (int kb = 0; kb < 9; ++kb)
        #pragma unroll
        for (int nf = 0; nf < 2; ++nf) {
            int n = o * 32 + nf * 16 + lr;
            breg[kb][nf] = *(const short8*)(W2b + n * CKK + kb * 32 + lg * 8);
        }

    // ---- hh tile -> LDS (padded 34) ----
    #pragma unroll
    for (int k = 0; k < 4; ++k) {
        int idx = k * 512 + t;                   // 2048 float4s
        int p = idx >> 3, h4 = (idx & 7) * 4;
        f32x4 v = *(const f32x4*)(hh_ws + (m0 + p) * 32 + h4);
        hh_lds[p * 34 + h4 + 0] = v[0];
        hh_lds[p * 34 + h4 + 1] = v[1];
        hh_lds[p * 34 + h4 + 2] = v[2];
        hh_lds[p * 34 + h4 + 3] = v[3];
    }

    // ---- prologue: stage kb=0 ----
    stage_a(u_ws + (0 * 32 + mtile) * 8192, &abuf[0][0], w, l);
    __syncthreads();

    f32x4 acc[8][2];
    #pragma unroll
    for (int mf = 0; mf < 8; ++mf) {
        acc[mf][0] = f32x4{0.f,0.f,0.f,0.f};
        acc[mf][1] = f32x4{0.f,0.f,0.f,0.f};
    }

    // ---- K-loop: 9 steps, double-buffered ----
    #pragma unroll
    for (int kb = 0; kb < 9; ++kb) {
        const int cur = kb & 1;
        if (kb < 8)
            stage_a(u_ws + ((kb + 1) * 32 + mtile) * 8192, &abuf[cur ^ 1][0], w, l);
        short8 a[8];
        #pragma unroll
        for (int mf = 0; mf < 8; ++mf)
            a[mf] = *(const short8*)(&abuf[cur][((mw * 8 + mf) * 64 + l) * 8]);
        #pragma unroll
        for (int mf = 0; mf < 8; ++mf) {
            acc[mf][0] = __builtin_amdgcn_mfma_f32_16x16x32_bf16(a[mf], breg[kb][0], acc[mf][0], 0, 0, 0);
            acc[mf][1] = __builtin_amdgcn_mfma_f32_16x16x32_bf16(a[mf], breg[kb][1], acc[mf][1], 0, 0, 0);
        }
        __syncthreads();  // drains stage (vmcnt) + all ds_reads before buffer swap
    }

    // ---- epilogue: reduce over h ----
    #pragma unroll
    for (int mf = 0; mf < 8; ++mf) {
        #pragma unroll
        for (int r = 0; r < 4; ++r) {
            int p = mw * 128 + mf * 16 + lg * 4 + r;
            float v = hh_lds[p * 34 + lr]      * acc[mf][0][r]
                    + hh_lds[p * 34 + 16 + lr] * acc[mf][1][r];
            v += __shfl_xor(v, 1);
            v += __shfl_xor(v, 2);
            v += __shfl_xor(v, 4);
            v += __shfl_xor(v, 8);
            if (lr == 0) o_lds[p * 5 + nw] = v;
        }
    }
    __syncthreads();

    // ---- coalesced store: 4 o-rows x 256 pixels ----
    #pragma unroll
    for (int k = 0; k < 2; ++k) {
        int idx = k * 512 + t;
        int oj = idx >> 8, p = idx & 255;
        int gp = m0 + p;
        float val = o_lds[p * 5 + oj] + t_ws[(o0 + oj) * 8192 + gp];
        int bb = gp >> 12;
        out[((size_t)(bb * 32 + o0 + oj)) * 4096 + (gp & 4095)] = val;
    }
}

extern "C" void kernel_launch(void* const* d_in, const int* in_sizes, int n_in,
                              void* d_out, int out_size, void* d_ws, size_t ws_size,
                              hipStream_t stream) {
    const float* x    = (const float*)d_in[0];
    const float* W1   = (const float*)d_in[1];
    const float* b1   = (const float*)d_in[2];
    const float* W2   = (const float*)d_in[3];
    const float* b2   = (const float*)d_in[4];
    const float* bias = (const float*)d_in[5];
    float* out = (float*)d_out;
    char* ws = (char*)d_ws;

    dynaconv_up<<<256, 512, 0, stream>>>(x, W1, b1, W2, b2, bias, ws);
    dynaconv_g<<<256, 512, 0, stream>>>(ws, out);
}